// Round 8
// baseline (161.904 us; speedup 1.0000x reference)
//
#include <hip/hip_runtime.h>
#include <math.h>

#define BB 256
#define FF 39
#define EE 16
#define II 741
#define BN_EPS 1e-5f
#define CPW 8            // channels per wave
#define NB 4             // batches per tile
#define NCX 24           // channel-blocks (ceil(741/32))
#define NGY (BB / NB)    // batch groups = 64
#define NTILE (NCX * NGY)  // 1536
#define NBLK 512         // grid; co-residency guaranteed at 2 blocks/CU

typedef float vfloat4 __attribute__((ext_vector_type(4)));
typedef float vfloat2 __attribute__((ext_vector_type(2)));

// Compile-time strict-lower-triangle offsets: v[i] = (r*EE)<<16 | (c*EE),
// row-major pair order matching np.tril_indices(F, -1).
struct OffTab { unsigned int v[II]; };
static constexpr OffTab make_off() {
    OffTab t{};
    int i = 0;
    for (int r = 1; r < FF; ++r)
        for (int c = 0; c < r; ++c) {
            t.v[i] = ((unsigned)(r * EE) << 16) | (unsigned)(c * EE);
            ++i;
        }
    return t;
}
__constant__ OffTab g_off = make_off();

// ws layout: [0] unsigned barrier counter (memset to 0 each launch);
//            +256 B: T2[I] = (a, d) per channel (~6 KB).
//
// Single kernel, manual grid barrier:
//  Phase A: first 741 global waves each reduce one channel's BN stats
//           directly from xi/xj (L2-resident), fold into affine (a,d).
//  release fence -> atomicAdd arrive -> acquire spin -> fence
//  Phase B: 1536 tiles (24 channel-blocks x 64 batch-groups), 3 per block;
//           per tile each wave owns 8 channels x 4 batches and streams
//           8 contiguous-1KB stores per batch.
__global__ __launch_bounds__(256, 2) void
fused_kernel(const float* __restrict__ xi,
             const float* __restrict__ xj,
             const float* __restrict__ W,
             const float* __restrict__ gamma,
             const float* __restrict__ beta,
             float* __restrict__ ws,
             float* __restrict__ out) {
    int t = threadIdx.x;
    int l = t & 63;        // lane in wave
    int wv = t >> 6;       // wave id 0..3

    unsigned* counter = reinterpret_cast<unsigned*>(ws);
    float* tbl = ws + 64;  // T2 base (256 B offset)

    // ---------------- Phase A: BN stats, one wave per channel ----------------
    int w = blockIdx.x * 4 + wv;   // global wave id
    if (w < II) {
        int i = w;
        unsigned o = g_off.v[i];
        int joff = (int)(o >> 16);
        int coff = (int)(o & 0xffffu);

        float sumS = 0.f, sumQ = 0.f;
#pragma unroll
        for (int b = l; b < BB; b += 64) {
            const vfloat4* xjr = reinterpret_cast<const vfloat4*>(xj + b * FF * EE + joff);
            const vfloat4* xic = reinterpret_cast<const vfloat4*>(xi + b * FF * EE + coff);
            float sj = 0.f, qj = 0.f, si = 0.f, qi = 0.f;
#pragma unroll
            for (int k = 0; k < 4; ++k) {
                vfloat4 vj = xjr[k];
                vfloat4 vi = xic[k];
                sj += vj.x + vj.y + vj.z + vj.w;
                qj += vj.x * vj.x + vj.y * vj.y + vj.z * vj.z + vj.w * vj.w;
                si += vi.x + vi.y + vi.z + vi.w;
                qi += vi.x * vi.x + vi.y * vi.y + vi.z * vi.z + vi.w * vi.w;
            }
            sumS += sj * si;
            sumQ += qj * qi;
        }
#pragma unroll
        for (int off = 32; off > 0; off >>= 1) {
            sumS += __shfl_xor(sumS, off);
            sumQ += __shfl_xor(sumQ, off);
        }
        if (l == 0) {
            const float invN = 1.0f / (float)(BB * EE * EE);  // 1/65536
            float mean = sumS * invN;
            float ex2 = sumQ * invN;
            float var = ex2 - mean * mean;
            float inv_std = 1.0f / sqrtf(var + BN_EPS);
            float a = gamma[i] * inv_std;
            float d = beta[i] - mean * a;
            vfloat2 e;
            e.x = a; e.y = d;
            reinterpret_cast<vfloat2*>(tbl)[i] = e;
        }
    }

    // ---------------- grid barrier (all 512 blocks co-resident) -------------
    __syncthreads();
    if (t == 0) {
        __threadfence();  // release: make T2 stores device-visible
        __hip_atomic_fetch_add(counter, 1u, __ATOMIC_ACQ_REL, __HIP_MEMORY_SCOPE_AGENT);
        while (__hip_atomic_load(counter, __ATOMIC_ACQUIRE, __HIP_MEMORY_SCOPE_AGENT) < NBLK) {
            __builtin_amdgcn_s_sleep(2);
        }
        __threadfence();  // acquire: discard stale T2 lines
    }
    __syncthreads();

    // ---------------- Phase B: streaming cross+BN+W multiply ----------------
    const vfloat2* T2 = reinterpret_cast<const vfloat2*>(tbl);
    int e1 = l >> 2;       // 0..15
    int e2q = l & 3;       // float4 index along e2

    vfloat4 w4 = reinterpret_cast<const vfloat4*>(W)[e1 * 4 + e2q];

#pragma unroll
    for (int rep = 0; rep < NTILE / NBLK; ++rep) {
        int tile = blockIdx.x + rep * NBLK;
        int cx = tile % NCX;
        int gy = tile / NCX;
        int ibase = __builtin_amdgcn_readfirstlane(cx * (4 * CPW) + wv * CPW);
        int b0 = gy * NB;

        if (ibase + CPW <= II) {
            // per-channel scalars (wave-uniform -> scalar loads)
            int joff[CPW], coff[CPW];
            float a[CPW], d[CPW];
#pragma unroll
            for (int k = 0; k < CPW; ++k) {
                unsigned o = g_off.v[ibase + k];
                joff[k] = (int)(o >> 16);
                coff[k] = (int)(o & 0xffffu);
                vfloat2 ad = T2[ibase + k];
                a[k] = ad.x; d[k] = ad.y;
            }
#pragma unroll
            for (int bb = 0; bb < NB; ++bb) {
                int b = b0 + bb;
                const float* xib = xi + b * FF * EE;
                const float* xjb = xj + b * FF * EE;
                float* outb = out + (size_t)b * (II * EE * EE) + (size_t)ibase * (EE * EE);
                float xjs[CPW];
                vfloat4 xi4[CPW];
#pragma unroll
                for (int k = 0; k < CPW; ++k) {
                    xjs[k] = xjb[joff[k] + e1];
                    xi4[k] = reinterpret_cast<const vfloat4*>(xib + coff[k])[e2q];
                }
#pragma unroll
                for (int k = 0; k < CPW; ++k) {
                    vfloat4 o4;
                    o4.x = (xjs[k] * xi4[k].x * a[k] + d[k]) * w4.x;
                    o4.y = (xjs[k] * xi4[k].y * a[k] + d[k]) * w4.y;
                    o4.z = (xjs[k] * xi4[k].z * a[k] + d[k]) * w4.z;
                    o4.w = (xjs[k] * xi4[k].w * a[k] + d[k]) * w4.w;
                    reinterpret_cast<vfloat4*>(outb + k * (EE * EE))[l] = o4;
                }
            }
        } else {
            // tail path (cx == 23 only; 741 = 23*32 + 5)
#pragma unroll
            for (int bb = 0; bb < NB; ++bb) {
                int b = b0 + bb;
                const float* xib = xi + b * FF * EE;
                const float* xjb = xj + b * FF * EE;
                float* outb = out + (size_t)b * (II * EE * EE);
                for (int k = 0; k < CPW; ++k) {
                    int i = ibase + k;
                    if (i >= II) break;  // wave-uniform
                    unsigned o = g_off.v[i];
                    int joff = (int)(o >> 16);
                    int coff = (int)(o & 0xffffu);
                    vfloat2 ad = T2[i];
                    float xjs = xjb[joff + e1];
                    vfloat4 xi4 = reinterpret_cast<const vfloat4*>(xib + coff)[e2q];
                    vfloat4 o4;
                    o4.x = (xjs * xi4.x * ad.x + ad.y) * w4.x;
                    o4.y = (xjs * xi4.y * ad.x + ad.y) * w4.y;
                    o4.z = (xjs * xi4.z * ad.x + ad.y) * w4.z;
                    o4.w = (xjs * xi4.w * ad.x + ad.y) * w4.w;
                    reinterpret_cast<vfloat4*>(outb + (size_t)i * (EE * EE))[l] = o4;
                }
            }
        }
    }
}

extern "C" void kernel_launch(void* const* d_in, const int* in_sizes, int n_in,
                              void* d_out, int out_size, void* d_ws, size_t ws_size,
                              hipStream_t stream) {
    const float* xi = (const float*)d_in[0];
    const float* xj = (const float*)d_in[1];
    const float* W = (const float*)d_in[2];
    const float* gamma = (const float*)d_in[3];
    const float* beta = (const float*)d_in[4];
    float* out = (float*)d_out;
    float* ws = (float*)d_ws;

    // zero the barrier counter (graph-capturable, deterministic each replay)
    hipMemsetAsync(ws, 0, sizeof(unsigned), stream);
    fused_kernel<<<dim3(NBLK), dim3(256), 0, stream>>>(xi, xj, W, gamma, beta, ws, out);
}

// Round 9
// 43.393 us; speedup vs baseline: 3.7311x; 3.7311x over previous
//
#include <hip/hip_runtime.h>
#include <math.h>

#define BB 256
#define FF 39
#define EE 16
#define II 741
#define BN_EPS 1e-5f
#define CPW 8   // channels per wave
#define NB 8    // batches per block (main kernel)
#define NCX 24  // channel-blocks: ceil(741/32)
#define NGY (BB / NB)  // 32

typedef float vfloat4 __attribute__((ext_vector_type(4)));
typedef float vfloat2 __attribute__((ext_vector_type(2)));

// Compile-time strict-lower-triangle offsets: v[i] = (r*EE)<<16 | (c*EE),
// row-major pair order matching np.tril_indices(F, -1).
struct OffTab { unsigned int v[II]; };
static constexpr OffTab make_off() {
    OffTab t{};
    int i = 0;
    for (int r = 1; r < FF; ++r)
        for (int c = 0; c < r; ++c) {
            t.v[i] = ((unsigned)(r * EE) << 16) | (unsigned)(c * EE);
            ++i;
        }
    return t;
}
__constant__ OffTab g_off = make_off();

// ws layout (floats): T2[I] = (a, d) per channel. ~6 KB.

// One wave per channel. Lanes split the batch dim; butterfly-reduce; lane 0
// folds BN stats into affine (a,d).
__global__ __launch_bounds__(256) void
stats_kernel(const float* __restrict__ xi,
             const float* __restrict__ xj,
             const float* __restrict__ gamma,
             const float* __restrict__ beta,
             float* __restrict__ ws) {
    int wid = (blockIdx.x * blockDim.x + threadIdx.x) >> 6;  // global wave = channel
    int lane = threadIdx.x & 63;
    if (wid >= II) return;
    int i = wid;
    unsigned o = g_off.v[i];
    int joff = (int)(o >> 16);
    int coff = (int)(o & 0xffffu);

    float sumS = 0.f, sumQ = 0.f;
#pragma unroll
    for (int b = lane; b < BB; b += 64) {
        const vfloat4* xjr = reinterpret_cast<const vfloat4*>(xj + b * FF * EE + joff);
        const vfloat4* xic = reinterpret_cast<const vfloat4*>(xi + b * FF * EE + coff);
        float sj = 0.f, qj = 0.f, si = 0.f, qi = 0.f;
#pragma unroll
        for (int k = 0; k < 4; ++k) {
            vfloat4 vj = xjr[k];
            vfloat4 vi = xic[k];
            sj += vj.x + vj.y + vj.z + vj.w;
            qj += vj.x * vj.x + vj.y * vj.y + vj.z * vj.z + vj.w * vj.w;
            si += vi.x + vi.y + vi.z + vi.w;
            qi += vi.x * vi.x + vi.y * vi.y + vi.z * vi.z + vi.w * vi.w;
        }
        sumS += sj * si;
        sumQ += qj * qi;
    }
#pragma unroll
    for (int off = 32; off > 0; off >>= 1) {
        sumS += __shfl_xor(sumS, off);
        sumQ += __shfl_xor(sumQ, off);
    }
    if (lane == 0) {
        const float invN = 1.0f / (float)(BB * EE * EE);  // 1/65536
        float mean = sumS * invN;
        float ex2 = sumQ * invN;
        float var = ex2 - mean * mean;
        float inv_std = 1.0f / sqrtf(var + BN_EPS);
        float a = gamma[i] * inv_std;
        float d = beta[i] - mean * a;
        vfloat2 e;
        e.x = a; e.y = d;
        reinterpret_cast<vfloat2*>(ws)[i] = e;
    }
}

// out[b,i,e1,e2] = ((xj[b,r,e1]*xi[b,c,e2]) * a[i] + d[i]) * W[e1,e2]
// 4 waves/block; wave owns 8 consecutive channels x 8 batches.
// Explicit 2-deep software pipeline over batches with named A/B buffers:
// loads for batch b+2 issue before the stores of batch b complete, so
// L2 load latency hides under the store stream.
#define LOADB(S, V, b)                                                        \
    {                                                                         \
        const float* xib_ = xi + (b) * FF * EE;                               \
        const float* xjb_ = xj + (b) * FF * EE;                               \
        _Pragma("unroll") for (int k = 0; k < CPW; ++k) {                     \
            S[k] = xjb_[joff[k] + e1];                                        \
            V[k] = reinterpret_cast<const vfloat4*>(xib_ + coff[k])[e2q];     \
        }                                                                     \
    }

#define STOREB(S, V, b)                                                       \
    {                                                                         \
        float* outb_ = out + (size_t)(b) * (II * EE * EE)                     \
                       + (size_t)ibase * (EE * EE);                           \
        _Pragma("unroll") for (int k = 0; k < CPW; ++k) {                     \
            vfloat4 o4;                                                       \
            o4.x = (S[k] * V[k].x * a[k] + d[k]) * w4.x;                      \
            o4.y = (S[k] * V[k].y * a[k] + d[k]) * w4.y;                      \
            o4.z = (S[k] * V[k].z * a[k] + d[k]) * w4.z;                      \
            o4.w = (S[k] * V[k].w * a[k] + d[k]) * w4.w;                      \
            reinterpret_cast<vfloat4*>(outb_ + k * (EE * EE))[l] = o4;        \
        }                                                                     \
    }

__global__ __launch_bounds__(256) void
cross_bn_kernel(const float* __restrict__ xi,
                const float* __restrict__ xj,
                const float* __restrict__ W,
                const float* __restrict__ ws,
                float* __restrict__ out) {
    const vfloat2* T2 = reinterpret_cast<const vfloat2*>(ws);

    int t = threadIdx.x;
    int l = t & 63;        // lane in wave
    int e1 = l >> 2;       // 0..15
    int e2q = l & 3;       // float4 index along e2
    int wv = t >> 6;       // wave id 0..3

    vfloat4 w4 = reinterpret_cast<const vfloat4*>(W)[e1 * 4 + e2q];

    int ibase = __builtin_amdgcn_readfirstlane(blockIdx.x * (4 * CPW) + wv * CPW);
    int b0 = blockIdx.y * NB;

    if (ibase + CPW <= II) {
        // per-channel scalars (wave-uniform -> scalar loads)
        int joff[CPW], coff[CPW];
        float a[CPW], d[CPW];
#pragma unroll
        for (int k = 0; k < CPW; ++k) {
            unsigned o = g_off.v[ibase + k];
            joff[k] = (int)(o >> 16);
            coff[k] = (int)(o & 0xffffu);
            vfloat2 ad = T2[ibase + k];
            a[k] = ad.x; d[k] = ad.y;
        }
        float sA[CPW], sB[CPW];
        vfloat4 vA[CPW], vB[CPW];
        // prologue: 2 batches in flight
        LOADB(sA, vA, b0 + 0)
        LOADB(sB, vB, b0 + 1)
        // steady state: store(b), then load(b+2) into the freed buffer
        STOREB(sA, vA, b0 + 0)  LOADB(sA, vA, b0 + 2)
        STOREB(sB, vB, b0 + 1)  LOADB(sB, vB, b0 + 3)
        STOREB(sA, vA, b0 + 2)  LOADB(sA, vA, b0 + 4)
        STOREB(sB, vB, b0 + 3)  LOADB(sB, vB, b0 + 5)
        STOREB(sA, vA, b0 + 4)  LOADB(sA, vA, b0 + 6)
        STOREB(sB, vB, b0 + 5)  LOADB(sB, vB, b0 + 7)
        STOREB(sA, vA, b0 + 6)
        STOREB(sB, vB, b0 + 7)
    } else {
        // tail path (blockIdx.x == 23; channels 736..740 on wave 0 only)
#pragma unroll
        for (int bb = 0; bb < NB; ++bb) {
            int b = b0 + bb;
            const float* xib = xi + b * FF * EE;
            const float* xjb = xj + b * FF * EE;
            float* outb = out + (size_t)b * (II * EE * EE);
            for (int k = 0; k < CPW; ++k) {
                int i = ibase + k;
                if (i >= II) break;  // wave-uniform
                unsigned o = g_off.v[i];
                int joff = (int)(o >> 16);
                int coff = (int)(o & 0xffffu);
                vfloat2 ad = T2[i];
                float xjs = xjb[joff + e1];
                vfloat4 xi4 = reinterpret_cast<const vfloat4*>(xib + coff)[e2q];
                vfloat4 o4;
                o4.x = (xjs * xi4.x * ad.x + ad.y) * w4.x;
                o4.y = (xjs * xi4.y * ad.x + ad.y) * w4.y;
                o4.z = (xjs * xi4.z * ad.x + ad.y) * w4.z;
                o4.w = (xjs * xi4.w * ad.x + ad.y) * w4.w;
                reinterpret_cast<vfloat4*>(outb + (size_t)i * (EE * EE))[l] = o4;
            }
        }
    }
}

extern "C" void kernel_launch(void* const* d_in, const int* in_sizes, int n_in,
                              void* d_out, int out_size, void* d_ws, size_t ws_size,
                              hipStream_t stream) {
    const float* xi = (const float*)d_in[0];
    const float* xj = (const float*)d_in[1];
    const float* W = (const float*)d_in[2];
    const float* gamma = (const float*)d_in[3];
    const float* beta = (const float*)d_in[4];
    float* out = (float*)d_out;
    float* ws = (float*)d_ws;

    stats_kernel<<<dim3((II * 64 + 255) / 256), 256, 0, stream>>>(xi, xj, gamma, beta, ws);
    cross_bn_kernel<<<dim3(NCX, NGY), 256, 0, stream>>>(xi, xj, W, ws, out);
}